// Round 5
// baseline (3837.919 us; speedup 1.0000x reference)
//
#include <hip/hip_runtime.h>

#define T_DIM 16
#define HW_DIM 4096
#define C_DIM 64
#define GN_EPS 1e-5f

__device__ __forceinline__ float leaky(float x) { return x > 0.f ? x : 0.01f * x; }

// One edge per lane. Weight matrices are read with wave-uniform addresses so the
// compiler emits s_load rows (broadcast via SGPR operand in v_fmac), and all
// per-edge 64-wide vectors live in VGPRs (every loop fully unrolled / rolled on
// the uniform k axis only).
__global__ __launch_bounds__(256, 1) void edge_kernel(
    const float* __restrict__ gf, const float* __restrict__ pos,
    const int* __restrict__ edge, const float* __restrict__ weight,
    const float* __restrict__ W1, const float* __restrict__ b1,
    const float* __restrict__ W2, const float* __restrict__ b2,
    const float* __restrict__ gdg, const float* __restrict__ gdb,
    const float* __restrict__ Wa, const float* __restrict__ ba,
    float* __restrict__ copyb, int* __restrict__ mask, int E)
{
    int e = blockIdx.x * blockDim.x + threadIdx.x;
    if (e >= E) return;

    const int4 ev = ((const int4*)edge)[e];  // eb, et, es, ed
    const int base = (ev.x * T_DIM + ev.y) * HW_DIM;
    const long flat_pre = (long)base + ev.z;
    const long flat_suc = (long)base + HW_DIM + ev.w;

    const float2 pp = ((const float2*)pos)[ev.y * HW_DIM + ev.z];
    const float2 ps = ((const float2*)pos)[(ev.y + 1) * HW_DIM + ev.w];
    const float pd0 = ps.x - pp.x;
    const float pd1 = ps.y - pp.y;

    // h = leaky_relu(pos_dist @ W1 + b1)
    float h[C_DIM];
#pragma unroll
    for (int c = 0; c < C_DIM; c++)
        h[c] = leaky(fmaf(pd0, W1[c], fmaf(pd1, W1[C_DIM + c], b1[c])));

    // d = h @ W2 + b2
    float d[C_DIM];
#pragma unroll
    for (int c = 0; c < C_DIM; c++) d[c] = b2[c];
#pragma unroll 4
    for (int k = 0; k < C_DIM; k++) {
        const float hk = h[k];
        const float* wr = W2 + k * C_DIM;  // wave-uniform row -> s_load
#pragma unroll
        for (int c = 0; c < C_DIM; c++) d[c] = fmaf(hk, wr[c], d[c]);
    }

    // group_norm(d) (per-lane reduction over the 64 regs)
    float s = 0.f, sq = 0.f;
#pragma unroll
    for (int c = 0; c < C_DIM; c++) { s += d[c]; sq = fmaf(d[c], d[c], sq); }
    const float mean = s * (1.f / C_DIM);
    const float var = sq * (1.f / C_DIM) - mean * mean;
    const float rs = rsqrtf(var + GN_EPS);

    // value gather: explicit float4 so the row load is 16x dwordx4
    const float4* vrow = (const float4*)(gf + flat_pre * C_DIM);
    float4 vv[C_DIM / 4];
#pragma unroll
    for (int q = 0; q < C_DIM / 4; q++) vv[q] = vrow[q];

    // u = value + dist_emb  (reuse h registers)
#pragma unroll
    for (int c = 0; c < C_DIM; c++) {
        const float v = ((const float*)vv)[c];
        h[c] = v + fmaf((d[c] - mean) * rs, gdg[c], gdb[c]);
    }

    // att = u @ Wa + ba  (reuse d registers)
#pragma unroll
    for (int c = 0; c < C_DIM; c++) d[c] = ba[c];
#pragma unroll 4
    for (int k = 0; k < C_DIM; k++) {
        const float uk = h[k];
        const float* wr = Wa + k * C_DIM;
#pragma unroll
        for (int c = 0; c < C_DIM; c++) d[c] = fmaf(uk, wr[c], d[c]);
    }

    const float w = weight[e];
    float* crow = copyb + flat_suc * C_DIM;
#pragma unroll
    for (int c = 0; c < C_DIM; c++) atomicAdd(crow + c, d[c] * w);
    mask[flat_suc] = 1;
}

// One node per lane; copyb == d_out (in-place: each row read then written by
// the same thread only).
__global__ __launch_bounds__(256, 1) void node_kernel(
    const float* __restrict__ gf, float* __restrict__ copyb,
    const int* __restrict__ mask,
    const float* __restrict__ gng, const float* __restrict__ gnb,
    const float* __restrict__ Wf, const float* __restrict__ bf,
    const float* __restrict__ gfg, const float* __restrict__ gfb, int N)
{
    int n = blockIdx.x * blockDim.x + threadIdx.x;
    if (n >= N) return;

    const float* grow = gf + (long)n * C_DIM;
    float* orow = copyb + (long)n * C_DIM;

    if (!mask[n]) {
        // out = gf
#pragma unroll
        for (int c = 0; c < C_DIM; c += 4)
            *(float4*)(orow + c) = *(const float4*)(grow + c);
        return;
    }

    float cat[2 * C_DIM];
    float s = 0.f, sq = 0.f;
#pragma unroll
    for (int k = 0; k < C_DIM; k++) {
        const float v = orow[k];  // accumulated copy
        cat[C_DIM + k] = v;
        s += v;
        sq = fmaf(v, v, sq);
    }
#pragma unroll
    for (int k = 0; k < C_DIM; k++) cat[k] = grow[k];

    float mean = s * (1.f / C_DIM);
    float var = sq * (1.f / C_DIM) - mean * mean;
    float rs = rsqrtf(var + GN_EPS);
#pragma unroll
    for (int k = 0; k < C_DIM; k++)
        cat[C_DIM + k] = fmaf((cat[C_DIM + k] - mean) * rs, gng[k], gnb[k]);

    // d = cat @ Wf + bf   (K = 128)
    float d[C_DIM];
#pragma unroll
    for (int c = 0; c < C_DIM; c++) d[c] = bf[c];
#pragma unroll 2
    for (int k = 0; k < 2 * C_DIM; k++) {
        const float ck = cat[k];
        const float* wr = Wf + k * C_DIM;  // wave-uniform -> s_load
#pragma unroll
        for (int c = 0; c < C_DIM; c++) d[c] = fmaf(ck, wr[c], d[c]);
    }

    s = 0.f; sq = 0.f;
#pragma unroll
    for (int c = 0; c < C_DIM; c++) { s += d[c]; sq = fmaf(d[c], d[c], sq); }
    mean = s * (1.f / C_DIM);
    var = sq * (1.f / C_DIM) - mean * mean;
    rs = rsqrtf(var + GN_EPS);

#pragma unroll
    for (int c = 0; c < C_DIM; c++)
        orow[c] = leaky(fmaf((d[c] - mean) * rs, gfg[c], gfb[c]));
}

extern "C" void kernel_launch(void* const* d_in, const int* in_sizes, int n_in,
                              void* d_out, int out_size, void* d_ws, size_t ws_size,
                              hipStream_t stream) {
    const float* gf     = (const float*)d_in[0];
    const float* pos    = (const float*)d_in[1];
    const int*   edge   = (const int*)d_in[2];
    const float* weight = (const float*)d_in[3];
    const float* W1  = (const float*)d_in[4];
    const float* b1  = (const float*)d_in[5];
    const float* W2  = (const float*)d_in[6];
    const float* b2  = (const float*)d_in[7];
    const float* gdg = (const float*)d_in[8];
    const float* gdb = (const float*)d_in[9];
    const float* Wa  = (const float*)d_in[10];
    const float* ba  = (const float*)d_in[11];
    const float* gng = (const float*)d_in[12];
    const float* gnb = (const float*)d_in[13];
    const float* Wf  = (const float*)d_in[14];
    const float* bf  = (const float*)d_in[15];
    const float* gfg = (const float*)d_in[16];
    const float* gfb = (const float*)d_in[17];

    float* out = (float*)d_out;
    const int E = in_sizes[3];            // weight has E elements
    const int N = in_sizes[0] / C_DIM;    // B*T*HW

    int* mask = (int*)d_ws;               // N ints

    // d_out doubles as the `copy` scatter accumulator; zero both (re-poisoned
    // to 0xAA before every timed launch).
    hipMemsetAsync(d_out, 0, (size_t)N * C_DIM * sizeof(float), stream);
    hipMemsetAsync(mask, 0, (size_t)N * sizeof(int), stream);

    dim3 blk(256);
    edge_kernel<<<dim3((E + 255) / 256), blk, 0, stream>>>(
        gf, pos, edge, weight, W1, b1, W2, b2, gdg, gdb, Wa, ba, out, mask, E);
    node_kernel<<<dim3((N + 255) / 256), blk, 0, stream>>>(
        gf, out, mask, gng, gnb, Wf, bf, gfg, gfb, N);
}

// Round 6
// 3767.999 us; speedup vs baseline: 1.0186x; 1.0186x over previous
//
#include <hip/hip_runtime.h>

#define T_DIM 16
#define HW_DIM 4096
#define C_DIM 64
#define GN_EPS 1e-5f

__device__ __forceinline__ float leaky(float x) { return x > 0.f ? x : 0.01f * x; }

// One edge per lane. ALL per-lane arrays are indexed with compile-time
// constants only (full unroll) so they live in VGPRs, never scratch.
// Weight matrices are read at wave-uniform addresses -> s_load broadcasts.
// Peak live state: 128 floats (two 64-vectors) per lane.
__global__ __launch_bounds__(256, 1) void edge_kernel(
    const float* __restrict__ gf, const float* __restrict__ pos,
    const int* __restrict__ edge, const float* __restrict__ weight,
    const float* __restrict__ W1, const float* __restrict__ b1,
    const float* __restrict__ W2, const float* __restrict__ b2,
    const float* __restrict__ gdg, const float* __restrict__ gdb,
    const float* __restrict__ Wa, const float* __restrict__ ba,
    float* __restrict__ copyb, int* __restrict__ mask, int E)
{
    int e = blockIdx.x * blockDim.x + threadIdx.x;
    if (e >= E) return;

    const int4 ev = ((const int4*)edge)[e];  // eb, et, es, ed
    const int base = (ev.x * T_DIM + ev.y) * HW_DIM;
    const long flat_pre = (long)base + ev.z;
    const long flat_suc = (long)base + HW_DIM + ev.w;

    const float2 pp = ((const float2*)pos)[ev.y * HW_DIM + ev.z];
    const float2 ps = ((const float2*)pos)[(ev.y + 1) * HW_DIM + ev.w];
    const float pd0 = ps.x - pp.x;
    const float pd1 = ps.y - pp.y;
    const float w = weight[e];

    // h = leaky_relu(pos_dist @ W1 + b1)
    float h[C_DIM];
#pragma unroll
    for (int c = 0; c < C_DIM; c++)
        h[c] = leaky(fmaf(pd0, W1[c], fmaf(pd1, W1[C_DIM + c], b1[c])));

    // d = h @ W2 + b2   (FULL unroll: h[k] is a constant-index register)
    float d[C_DIM];
#pragma unroll
    for (int c = 0; c < C_DIM; c++) d[c] = b2[c];
#pragma unroll
    for (int k = 0; k < C_DIM; k++) {
        const float hk = h[k];
#pragma unroll
        for (int c = 0; c < C_DIM; c++) d[c] = fmaf(hk, W2[k * C_DIM + c], d[c]);
    }
    // h is dead here.

    // group_norm stats of d (per-lane reduction over registers)
    float s = 0.f, sq = 0.f;
#pragma unroll
    for (int c = 0; c < C_DIM; c++) { s += d[c]; sq = fmaf(d[c], d[c], sq); }
    const float mean = s * (1.f / C_DIM);
    const float var = sq * (1.f / C_DIM) - mean * mean;
    const float rs = rsqrtf(var + GN_EPS);

    // u = value + dist_emb, in place (d -> u), value streamed as float4
    const float4* vrow = (const float4*)(gf + flat_pre * C_DIM);
#pragma unroll
    for (int q = 0; q < C_DIM / 4; q++) {
        const float4 v = vrow[q];
        d[4 * q + 0] = v.x + fmaf((d[4 * q + 0] - mean) * rs, gdg[4 * q + 0], gdb[4 * q + 0]);
        d[4 * q + 1] = v.y + fmaf((d[4 * q + 1] - mean) * rs, gdg[4 * q + 1], gdb[4 * q + 1]);
        d[4 * q + 2] = v.z + fmaf((d[4 * q + 2] - mean) * rs, gdg[4 * q + 2], gdb[4 * q + 2]);
        d[4 * q + 3] = v.w + fmaf((d[4 * q + 3] - mean) * rs, gdg[4 * q + 3], gdb[4 * q + 3]);
    }

    // att = u @ Wa + ba   (FULL unroll)
    float acc[C_DIM];
#pragma unroll
    for (int c = 0; c < C_DIM; c++) acc[c] = ba[c];
#pragma unroll
    for (int k = 0; k < C_DIM; k++) {
        const float uk = d[k];
#pragma unroll
        for (int c = 0; c < C_DIM; c++) acc[c] = fmaf(uk, Wa[k * C_DIM + c], acc[c]);
    }

    float* crow = copyb + flat_suc * C_DIM;
#pragma unroll
    for (int c = 0; c < C_DIM; c++) atomicAdd(crow + c, acc[c] * w);
    mask[flat_suc] = 1;
}

// One node per lane; copyb == d_out (in-place). K=128 GEMV split into two
// 64-deep fully-unrolled passes so only two 64-vectors are live at once:
// pass A streams the gf row from global, pass B consumes the normalized copy.
__global__ __launch_bounds__(256, 1) void node_kernel(
    const float* __restrict__ gf, float* __restrict__ copyb,
    const int* __restrict__ mask,
    const float* __restrict__ gng, const float* __restrict__ gnb,
    const float* __restrict__ Wf, const float* __restrict__ bf,
    const float* __restrict__ gfg, const float* __restrict__ gfb, int N)
{
    int n = blockIdx.x * blockDim.x + threadIdx.x;
    if (n >= N) return;

    const float* grow = gf + (long)n * C_DIM;
    float* orow = copyb + (long)n * C_DIM;

    if (!mask[n]) {
        // out = gf
#pragma unroll
        for (int c = 0; c < C_DIM; c += 4)
            *(float4*)(orow + c) = *(const float4*)(grow + c);
        return;
    }

    // load accumulated copy row + GN stats
    float cp[C_DIM];
    float s = 0.f, sq = 0.f;
#pragma unroll
    for (int q = 0; q < C_DIM / 4; q++) {
        const float4 v = ((const float4*)orow)[q];
        cp[4 * q + 0] = v.x; cp[4 * q + 1] = v.y;
        cp[4 * q + 2] = v.z; cp[4 * q + 3] = v.w;
        s += v.x + v.y + v.z + v.w;
        sq = fmaf(v.x, v.x, fmaf(v.y, v.y, fmaf(v.z, v.z, fmaf(v.w, v.w, sq))));
    }
    float mean = s * (1.f / C_DIM);
    float var = sq * (1.f / C_DIM) - mean * mean;
    float rs = rsqrtf(var + GN_EPS);

    float d[C_DIM];
#pragma unroll
    for (int c = 0; c < C_DIM; c++) d[c] = bf[c];

    // pass A: d += gf_row @ Wf[0:64]   (gf streamed, never all live)
#pragma unroll
    for (int q = 0; q < C_DIM / 4; q++) {
        const float4 g = ((const float4*)grow)[q];
        const float gs[4] = {g.x, g.y, g.z, g.w};
#pragma unroll
        for (int j = 0; j < 4; j++) {
            const float gk = gs[j];
            const int k = 4 * q + j;
#pragma unroll
            for (int c = 0; c < C_DIM; c++)
                d[c] = fmaf(gk, Wf[k * C_DIM + c], d[c]);
        }
    }

    // pass B: d += group_norm(copy) @ Wf[64:128]
#pragma unroll
    for (int k = 0; k < C_DIM; k++) {
        const float ck = fmaf((cp[k] - mean) * rs, gng[k], gnb[k]);
#pragma unroll
        for (int c = 0; c < C_DIM; c++)
            d[c] = fmaf(ck, Wf[(C_DIM + k) * C_DIM + c], d[c]);
    }

    // final group_norm + leaky, write out
    s = 0.f; sq = 0.f;
#pragma unroll
    for (int c = 0; c < C_DIM; c++) { s += d[c]; sq = fmaf(d[c], d[c], sq); }
    mean = s * (1.f / C_DIM);
    var = sq * (1.f / C_DIM) - mean * mean;
    rs = rsqrtf(var + GN_EPS);

#pragma unroll
    for (int q = 0; q < C_DIM / 4; q++) {
        float4 o;
        o.x = leaky(fmaf((d[4 * q + 0] - mean) * rs, gfg[4 * q + 0], gfb[4 * q + 0]));
        o.y = leaky(fmaf((d[4 * q + 1] - mean) * rs, gfg[4 * q + 1], gfb[4 * q + 1]));
        o.z = leaky(fmaf((d[4 * q + 2] - mean) * rs, gfg[4 * q + 2], gfb[4 * q + 2]));
        o.w = leaky(fmaf((d[4 * q + 3] - mean) * rs, gfg[4 * q + 3], gfb[4 * q + 3]));
        ((float4*)orow)[q] = o;
    }
}

extern "C" void kernel_launch(void* const* d_in, const int* in_sizes, int n_in,
                              void* d_out, int out_size, void* d_ws, size_t ws_size,
                              hipStream_t stream) {
    const float* gf     = (const float*)d_in[0];
    const float* pos    = (const float*)d_in[1];
    const int*   edge   = (const int*)d_in[2];
    const float* weight = (const float*)d_in[3];
    const float* W1  = (const float*)d_in[4];
    const float* b1  = (const float*)d_in[5];
    const float* W2  = (const float*)d_in[6];
    const float* b2  = (const float*)d_in[7];
    const float* gdg = (const float*)d_in[8];
    const float* gdb = (const float*)d_in[9];
    const float* Wa  = (const float*)d_in[10];
    const float* ba  = (const float*)d_in[11];
    const float* gng = (const float*)d_in[12];
    const float* gnb = (const float*)d_in[13];
    const float* Wf  = (const float*)d_in[14];
    const float* bf  = (const float*)d_in[15];
    const float* gfg = (const float*)d_in[16];
    const float* gfb = (const float*)d_in[17];

    float* out = (float*)d_out;
    const int E = in_sizes[3];            // weight has E elements
    const int N = in_sizes[0] / C_DIM;    // B*T*HW

    int* mask = (int*)d_ws;               // N ints

    // d_out doubles as the `copy` scatter accumulator; zero both (re-poisoned
    // to 0xAA before every timed launch).
    hipMemsetAsync(d_out, 0, (size_t)N * C_DIM * sizeof(float), stream);
    hipMemsetAsync(mask, 0, (size_t)N * sizeof(int), stream);

    dim3 blk(256);
    edge_kernel<<<dim3((E + 255) / 256), blk, 0, stream>>>(
        gf, pos, edge, weight, W1, b1, W2, b2, gdg, gdb, Wa, ba, out, mask, E);
    node_kernel<<<dim3((N + 255) / 256), blk, 0, stream>>>(
        gf, out, mask, gng, gnb, Wf, bf, gfg, gfb, N);
}